// Round 4
// baseline (10043.751 us; speedup 1.0000x reference)
//
#include <hip/hip_runtime.h>
#include <cstdint>
#include <cstddef>

#define S 4096
#define E 256
#define H 256
#define GATES 1024
#define T 32
#define START_TAG 30
#define STOP_TAG 31
#define NEGV (-10000.0f)

typedef _Float16 half_t;
typedef _Float16 h2 __attribute__((ext_vector_type(2)));

__device__ __forceinline__ h2 f2h2(float a, float b) {
    h2 r; r[0] = (half_t)a; r[1] = (half_t)b; return r;
}
__device__ __forceinline__ h2 u2h2(unsigned int u) {
    h2 r; __builtin_memcpy(&r, &u, 4); return r;
}
__device__ __forceinline__ unsigned int h22u(h2 v) {
    unsigned int u; __builtin_memcpy(&u, &v, 4); return u;
}
__device__ __forceinline__ unsigned short f2h16(float f) {
    half_t h = (half_t)f;
    unsigned short u; __builtin_memcpy(&u, &h, 2); return u;
}
__device__ __forceinline__ float h16tof(unsigned short u) {
    half_t h; __builtin_memcpy(&h, &u, 2); return (float)h;
}

#if __has_builtin(__builtin_amdgcn_fdot2)
__device__ __forceinline__ float dot2(h2 a, h2 b, float c) {
    return __builtin_amdgcn_fdot2(a, b, c, false);
}
#else
__device__ __forceinline__ float dot2(h2 a, h2 b, float c) {
    return c + (float)a[0] * (float)b[0] + (float)a[1] * (float)b[1];
}
#endif

__device__ __forceinline__ float sigmoidf_(float x) {
    return 1.0f / (1.0f + __expf(-x));
}
__device__ __forceinline__ float tanhf_(float x) {
    return 1.0f - 2.0f / (__expf(2.0f * x) + 1.0f);
}

union W64 { unsigned long long u; h2 h[2]; };

// ---------------------------------------------------------------------------
// Kernel 0: convert the L2-streamed remainder of W_hh (pairs 107..127) to f16,
// packed per (dir, slot s=0..20, tid): {row tid pair(107+s), row 512+tid pair(107+s)}
// ---------------------------------------------------------------------------
#define NRP 21
__global__ __launch_bounds__(512) void wrem_prep_kernel(
    const float* __restrict__ w_hh_f, const float* __restrict__ w_hh_b,
    unsigned long long* __restrict__ wrem)
{
    const int s = blockIdx.x;        // 0..20
    const int dir = blockIdx.y;      // 0..1
    const int tid = threadIdx.x;     // 0..511
    const float* w_hh = dir ? w_hh_b : w_hh_f;
    const int pair = 107 + s;
    float2 a = *(const float2*)(w_hh + (size_t)tid * H + 2 * pair);
    float2 b = *(const float2*)(w_hh + (size_t)(512 + tid) * H + 2 * pair);
    W64 w; w.h[0] = f2h2(a.x, a.y); w.h[1] = f2h2(b.x, b.y);
    wrem[((size_t)dir * NRP + s) * 512 + tid] = w.u;
}

// ---------------------------------------------------------------------------
// Kernel 1: xg packed f16: word (dir,t,col) = {gate row col, gate row col+512}
// ---------------------------------------------------------------------------
#define SBLK 16
__global__ __launch_bounds__(256) void xg_kernel(
    const int* __restrict__ sent, const float* __restrict__ emb,
    const float* __restrict__ w_ih_f, const float* __restrict__ b_f,
    const float* __restrict__ w_ih_b, const float* __restrict__ b_b,
    unsigned short* __restrict__ xg16s)   // viewed as ushort[2*S*512*2]
{
    const int dir = blockIdx.y;
    const int t0 = blockIdx.x * SBLK;
    const float* w_ih = dir ? w_ih_b : w_ih_f;
    const float* bias = dir ? b_b : b_f;

    __shared__ float embs[SBLK][E];   // 16 KB
    for (int p = threadIdx.x; p < SBLK * (E / 4); p += 256) {
        int r = p >> 6, kq = p & 63;
        int t = t0 + r;
        int tt = dir ? (S - 1 - t) : t;
        int tok = sent[tt];
        float4 v = *(const float4*)(emb + (size_t)tok * E + 4 * kq);
        *(float4*)&embs[r][4 * kq] = v;
    }
    __syncthreads();

    for (int jj = 0; jj < 4; ++jj) {
        int j = jj * 256 + threadIdx.x;
        const float* wrow = w_ih + (size_t)j * E;
        float bv = bias[j];
        float acc[SBLK];
        #pragma unroll
        for (int t = 0; t < SBLK; ++t) acc[t] = bv;

        for (int kc = 0; kc < E / 16; ++kc) {
            float w[16];
            float4 a0 = *(const float4*)(wrow + kc * 16);
            float4 a1 = *(const float4*)(wrow + kc * 16 + 4);
            float4 a2 = *(const float4*)(wrow + kc * 16 + 8);
            float4 a3 = *(const float4*)(wrow + kc * 16 + 12);
            w[0] = a0.x; w[1] = a0.y; w[2] = a0.z; w[3] = a0.w;
            w[4] = a1.x; w[5] = a1.y; w[6] = a1.z; w[7] = a1.w;
            w[8] = a2.x; w[9] = a2.y; w[10] = a2.z; w[11] = a2.w;
            w[12] = a3.x; w[13] = a3.y; w[14] = a3.z; w[15] = a3.w;
            #pragma unroll
            for (int t = 0; t < SBLK; ++t) {
                const float* er = &embs[t][kc * 16];
                float s = 0.f;
                #pragma unroll
                for (int q = 0; q < 16; ++q) s += w[q] * er[q];
                acc[t] += s;
            }
        }
        const int col = j & 511;
        const int hi = j >> 9;
        #pragma unroll
        for (int t = 0; t < SBLK; ++t) {
            size_t word = ((size_t)dir * S + (size_t)(t0 + t)) * 512 + col;
            xg16s[word * 2 + hi] = f2h16(acc[t]);
        }
    }
}

// ---------------------------------------------------------------------------
// Kernel 2: persistent per-direction LSTM. 2 blocks x 512 threads, <=64KB LDS.
// Thread tid owns gate rows r0=tid, r1=512+tid.
// W_hh pairs/row: 0..91 VGPR, 92..106 LDS, 107..127 streamed from L2 (wrem).
// ---------------------------------------------------------------------------
__global__ __launch_bounds__(512, 2) void lstm_kernel(
    const float* __restrict__ h0, const float* __restrict__ c0,
    const float* __restrict__ w_hh_f, const float* __restrict__ w_hh_b,
    const unsigned long long* __restrict__ wrem,
    const unsigned int* __restrict__ xg16, float* __restrict__ hs)
{
    __shared__ struct {
        unsigned long long wl64[2][7][512];   // pairs 92..105 (slot pairs)
        unsigned int       wl32[2][512];      // pair 106
        unsigned int       hbuf[128];         // h as f16x2
        float              fo[512];           // f,o exchange
    } sm;                                     // 57344+4096+512+2048 = 64000 B

    const int dir = blockIdx.x;
    const int tid = threadIdx.x;
    const float* w_hh = dir ? w_hh_b : w_hh_f;
    const int r0 = tid, r1 = 512 + tid;

    // ---- load weights (f32 -> f16) ----
    h2 wr0[92], wr1[92];
    {
        const float* p0 = w_hh + (size_t)r0 * H;
        const float* p1 = w_hh + (size_t)r1 * H;
        #pragma unroll
        for (int p = 0; p < 92; ++p) {
            float2 a = *(const float2*)(p0 + 2 * p);
            float2 b = *(const float2*)(p1 + 2 * p);
            wr0[p] = f2h2(a.x, a.y);
            wr1[p] = f2h2(b.x, b.y);
        }
        #pragma unroll
        for (int s = 0; s < 7; ++s) {
            float4 a = *(const float4*)(p0 + 184 + 4 * s);
            W64 wa; wa.h[0] = f2h2(a.x, a.y); wa.h[1] = f2h2(a.z, a.w);
            sm.wl64[0][s][tid] = wa.u;
            float4 b = *(const float4*)(p1 + 184 + 4 * s);
            W64 wb; wb.h[0] = f2h2(b.x, b.y); wb.h[1] = f2h2(b.z, b.w);
            sm.wl64[1][s][tid] = wb.u;
        }
        float2 a = *(const float2*)(p0 + 212);
        float2 b = *(const float2*)(p1 + 212);
        sm.wl32[0][tid] = h22u(f2h2(a.x, a.y));
        sm.wl32[1][tid] = h22u(f2h2(b.x, b.y));
    }

    float c = 0.f;
    if (tid < 256) c = c0[dir * H + tid];
    if (tid < 128) {
        float2 u = *(const float2*)(h0 + dir * H + 2 * tid);
        sm.hbuf[tid] = h22u(f2h2(u.x, u.y));
    }
    __syncthreads();

    const unsigned int* xgp = xg16 + (size_t)dir * S * 512 + tid;
    const unsigned long long* wremp = wrem + (size_t)dir * NRP * 512 + tid;
    const uint4* hb4 = (const uint4*)sm.hbuf;
    half_t* hhalf = (half_t*)sm.hbuf;

    unsigned int xgw = xgp[0];

    for (int t = 0; t < S; ++t) {
        int tn = (t + 1 < S) ? (t + 1) : t;
        unsigned int xgn = xgp[(size_t)tn * 512];

        float acc0 = 0.f, acc1 = 0.f;

        #pragma unroll
        for (int cc = 0; cc < 16; ++cc) {
            uint4 hv = hb4[cc];
            h2 hh0 = u2h2(hv.x), hh1 = u2h2(hv.y), hh2 = u2h2(hv.z), hh3 = u2h2(hv.w);
            acc0 = dot2(wr0[cc * 4 + 0], hh0, acc0);
            acc0 = dot2(wr0[cc * 4 + 1], hh1, acc0);
            acc0 = dot2(wr0[cc * 4 + 2], hh2, acc0);
            acc0 = dot2(wr0[cc * 4 + 3], hh3, acc0);
            acc1 = dot2(wr1[cc * 4 + 0], hh0, acc1);
            acc1 = dot2(wr1[cc * 4 + 1], hh1, acc1);
            acc1 = dot2(wr1[cc * 4 + 2], hh2, acc1);
            acc1 = dot2(wr1[cc * 4 + 3], hh3, acc1);
        }

        W64 rem[NRP];
        #pragma unroll
        for (int s = 0; s < NRP; ++s) rem[s].u = wremp[(size_t)s * 512];

        #pragma unroll
        for (int cc = 16; cc < 23; ++cc) {
            uint4 hv = hb4[cc];
            h2 hh0 = u2h2(hv.x), hh1 = u2h2(hv.y), hh2 = u2h2(hv.z), hh3 = u2h2(hv.w);
            acc0 = dot2(wr0[cc * 4 + 0], hh0, acc0);
            acc0 = dot2(wr0[cc * 4 + 1], hh1, acc0);
            acc0 = dot2(wr0[cc * 4 + 2], hh2, acc0);
            acc0 = dot2(wr0[cc * 4 + 3], hh3, acc0);
            acc1 = dot2(wr1[cc * 4 + 0], hh0, acc1);
            acc1 = dot2(wr1[cc * 4 + 1], hh1, acc1);
            acc1 = dot2(wr1[cc * 4 + 2], hh2, acc1);
            acc1 = dot2(wr1[cc * 4 + 3], hh3, acc1);
        }

        #pragma unroll
        for (int cc = 23; cc < 32; ++cc) {
            uint4 hv = hb4[cc];
            h2 hh[4] = {u2h2(hv.x), u2h2(hv.y), u2h2(hv.z), u2h2(hv.w)};
            h2 a[4], b[4];
            if (cc < 26) {
                int s0 = (cc - 23) * 2;
                W64 x0, x1, y0, y1;
                x0.u = sm.wl64[0][s0][tid];     x1.u = sm.wl64[0][s0 + 1][tid];
                y0.u = sm.wl64[1][s0][tid];     y1.u = sm.wl64[1][s0 + 1][tid];
                a[0] = x0.h[0]; a[1] = x0.h[1]; a[2] = x1.h[0]; a[3] = x1.h[1];
                b[0] = y0.h[0]; b[1] = y0.h[1]; b[2] = y1.h[0]; b[3] = y1.h[1];
            } else if (cc == 26) {
                W64 x0, y0;
                x0.u = sm.wl64[0][6][tid];
                y0.u = sm.wl64[1][6][tid];
                a[0] = x0.h[0]; a[1] = x0.h[1]; a[2] = u2h2(sm.wl32[0][tid]); a[3] = rem[0].h[0];
                b[0] = y0.h[0]; b[1] = y0.h[1]; b[2] = u2h2(sm.wl32[1][tid]); b[3] = rem[0].h[1];
            } else {
                int s = (cc - 27) * 4 + 1;
                a[0] = rem[s].h[0]; a[1] = rem[s + 1].h[0]; a[2] = rem[s + 2].h[0]; a[3] = rem[s + 3].h[0];
                b[0] = rem[s].h[1]; b[1] = rem[s + 1].h[1]; b[2] = rem[s + 2].h[1]; b[3] = rem[s + 3].h[1];
            }
            #pragma unroll
            for (int k = 0; k < 4; ++k) {
                acc0 = dot2(a[k], hh[k], acc0);
                acc1 = dot2(b[k], hh[k], acc1);
            }
        }

        float g0 = h16tof((unsigned short)(xgw & 0xffffu)) + acc0;
        float g1 = h16tof((unsigned short)(xgw >> 16)) + acc1;
        float ig = 0.f, gg = 0.f;
        if (tid < 256) {
            ig = sigmoidf_(g0);     // input gate
            gg = tanhf_(g1);        // candidate
        } else {
            sm.fo[tid - 256] = sigmoidf_(g0);          // forget gate
            sm.fo[256 + (tid - 256)] = sigmoidf_(g1);  // output gate
        }
        __syncthreads();
        if (tid < 256) {
            float f = sm.fo[tid], o = sm.fo[256 + tid];
            c = f * c + ig * gg;
            float hv2 = o * tanhf_(c);
            int row = dir ? (S - 1 - t) : t;
            hs[(size_t)row * 512 + dir * 256 + tid] = hv2;
            hhalf[tid] = (half_t)hv2;
        }
        xgw = xgn;
        __syncthreads();
    }
}

// ---------------------------------------------------------------------------
// Kernel 3: feats[t][tag] = lin_b[tag] + sum_k hs[t][k] * lin_w[tag][k]
// ---------------------------------------------------------------------------
__global__ __launch_bounds__(256) void feats_kernel(
    const float* __restrict__ hs, const float* __restrict__ lin_w,
    const float* __restrict__ lin_b, float* __restrict__ feats)
{
    const int t0 = blockIdx.x * 8;
    __shared__ float rows[8][512];   // 16 KB
    for (int p = threadIdx.x; p < 8 * 128; p += 256) {
        int r = p >> 7, sg = p & 127;
        float4 v = *(const float4*)(hs + (size_t)(t0 + r) * 512 + sg * 4);
        *(float4*)&rows[r][sg * 4] = v;
    }
    __syncthreads();

    const int tl = threadIdx.x >> 5, tag = threadIdx.x & 31;
    const float* lw = lin_w + (size_t)tag * 512;
    float acc = lin_b[tag];
    for (int kc = 0; kc < 32; ++kc) {
        float4 a0 = *(const float4*)(lw + kc * 16);
        float4 a1 = *(const float4*)(lw + kc * 16 + 4);
        float4 a2 = *(const float4*)(lw + kc * 16 + 8);
        float4 a3 = *(const float4*)(lw + kc * 16 + 12);
        const float* er = &rows[tl][kc * 16];
        acc += a0.x * er[0] + a0.y * er[1] + a0.z * er[2] + a0.w * er[3];
        acc += a1.x * er[4] + a1.y * er[5] + a1.z * er[6] + a1.w * er[7];
        acc += a2.x * er[8] + a2.y * er[9] + a2.z * er[10] + a2.w * er[11];
        acc += a3.x * er[12] + a3.y * er[13] + a3.z * er[14] + a3.w * er[15];
    }
    feats[(size_t)(t0 + tl) * T + tag] = acc;
}

// ---------------------------------------------------------------------------
// Kernel 4: Viterbi scan (wave 0) + chunked-parallel backtrack. 1 block x 256.
// OUTPUT IS FLOAT32: out[0]=score, out[1+t]=(float)tag.
// ---------------------------------------------------------------------------
#define NC 64
#define CS 64
__global__ __launch_bounds__(256) void viterbi_kernel(
    const float* __restrict__ feats, const float* __restrict__ trans,
    unsigned char* __restrict__ gbp, float* __restrict__ out)
{
    __shared__ float fvbuf[32];
    __shared__ float fin[32];
    __shared__ unsigned char Mmap[NC][32];
    __shared__ int ent[NC];
    __shared__ int lastsh;

    volatile float* fv = fvbuf;
    const int tid = threadIdx.x;

    if (tid < 64) {
        const int nt = tid & 31, hf = tid >> 5;
        float tr[16];
        #pragma unroll
        for (int q = 0; q < 16; ++q) tr[q] = trans[nt * T + hf * 16 + q];

        if (hf == 0) fv[nt] = (nt == START_TAG) ? 0.f : NEGV;

        float featv = feats[nt];
        for (int t = 0; t < S; ++t) {
            float featn = feats[(size_t)((t + 1 < S) ? (t + 1) : t) * T + nt];
            float m = -3.0e38f; int bi = 0;
            #pragma unroll
            for (int q = 0; q < 16; ++q) {
                float s2 = fv[hf * 16 + q] + tr[q];
                if (s2 > m) { m = s2; bi = hf * 16 + q; }
            }
            float m2 = __shfl(m, tid ^ 32);
            int b2 = __shfl(bi, tid ^ 32);
            if (hf == 0) {
                if (m2 > m) { m = m2; bi = b2; }   // low half wins ties (first-max)
                fv[nt] = m + featv;
                gbp[t * T + nt] = (unsigned char)bi;
            }
            featv = featn;
        }

        if (hf == 0) fin[nt] = fv[nt] + trans[STOP_TAG * T + nt];
        if (tid == 0) {
            float bm = -3.0e38f; int bl = 0;
            for (int j = 0; j < T; ++j) {
                if (fin[j] > bm) { bm = fin[j]; bl = j; }
            }
            out[0] = bm;               // score as float32
            lastsh = bl;
        }
    }
    __threadfence_block();
    __syncthreads();

    // Phase A: per-chunk tag maps (walk each 64-step chunk from every end tag)
    {
        int st[8], cc[8];
        #pragma unroll
        for (int k = 0; k < 8; ++k) {
            int it = tid + k * 256;
            cc[k] = it >> 5; st[k] = it & 31;
        }
        for (int s = 0; s < CS; ++s) {
            #pragma unroll
            for (int k = 0; k < 8; ++k) {
                st[k] = gbp[(cc[k] * CS + CS - 1 - s) * T + st[k]];
            }
        }
        #pragma unroll
        for (int k = 0; k < 8; ++k) {
            Mmap[cc[k]][(tid + k * 256) & 31] = (unsigned char)st[k];
        }
    }
    __syncthreads();

    // Phase B: sequential composition of 64 chunk maps (1 thread)
    if (tid == 0) {
        int cur = lastsh;
        ent[NC - 1] = cur;
        for (int cchunk = NC - 1; cchunk > 0; --cchunk) {
            cur = Mmap[cchunk][cur];
            ent[cchunk - 1] = cur;
        }
    }
    __syncthreads();

    // Phase C: each chunk writes its path segment (float32 tags)
    if (tid < NC) {
        int cchunk = tid;
        int cur = ent[cchunk];
        for (int i = CS - 1; i >= 0; --i) {
            int t = cchunk * CS + i;
            out[1 + t] = (float)cur;
            cur = gbp[t * T + cur];
        }
    }
}

// ---------------------------------------------------------------------------
extern "C" void kernel_launch(void* const* d_in, const int* in_sizes, int n_in,
                              void* d_out, int out_size, void* d_ws, size_t ws_size,
                              hipStream_t stream)
{
    const int* sent      = (const int*)d_in[0];
    const float* h0      = (const float*)d_in[1];
    const float* c0      = (const float*)d_in[2];
    const float* emb     = (const float*)d_in[3];
    const float* w_ih_f  = (const float*)d_in[4];
    const float* w_hh_f  = (const float*)d_in[5];
    const float* b_f     = (const float*)d_in[6];
    const float* w_ih_b  = (const float*)d_in[7];
    const float* w_hh_b  = (const float*)d_in[8];
    const float* b_b     = (const float*)d_in[9];
    const float* lin_w   = (const float*)d_in[10];
    const float* lin_b   = (const float*)d_in[11];
    const float* trans   = (const float*)d_in[12];
    float* out = (float*)d_out;

    // workspace layout (~26 MB)
    unsigned int* xg16   = (unsigned int*)d_ws;                          // [2][S][512] u32 = 16 MB
    float* hs            = (float*)(xg16 + (size_t)2 * S * 512);         // [S][512] f32 = 8 MB
    float* feats         = hs + (size_t)S * 512;                         // [S][32] f32 = 0.5 MB
    unsigned char* gbp   = (unsigned char*)(feats + (size_t)S * T);      // [S][32] = 128 KB
    unsigned long long* wrem = (unsigned long long*)(gbp + (size_t)S * T); // [2][21][512] u64 = 168 KB

    wrem_prep_kernel<<<dim3(NRP, 2), 512, 0, stream>>>(w_hh_f, w_hh_b, wrem);
    xg_kernel<<<dim3(S / SBLK, 2), 256, 0, stream>>>(sent, emb, w_ih_f, b_f, w_ih_b, b_b,
                                                     (unsigned short*)xg16);
    lstm_kernel<<<2, 512, 0, stream>>>(h0, c0, w_hh_f, w_hh_b, wrem, xg16, hs);
    feats_kernel<<<S / 8, 256, 0, stream>>>(hs, lin_w, lin_b, feats);
    viterbi_kernel<<<1, 256, 0, stream>>>(feats, trans, gbp, out);
}

// Round 5
// 8736.979 us; speedup vs baseline: 1.1496x; 1.1496x over previous
//
#include <hip/hip_runtime.h>
#include <cstdint>
#include <cstddef>

#define S 4096
#define E 256
#define H 256
#define GATES 1024
#define T 32
#define START_TAG 30
#define STOP_TAG 31
#define NEGV (-10000.0f)

typedef _Float16 half_t;
typedef _Float16 h2 __attribute__((ext_vector_type(2)));

__device__ __forceinline__ h2 f2h2(float a, float b) {
    h2 r; r[0] = (half_t)a; r[1] = (half_t)b; return r;
}
__device__ __forceinline__ h2 u2h2(unsigned int u) {
    h2 r; __builtin_memcpy(&r, &u, 4); return r;
}
__device__ __forceinline__ unsigned int h22u(h2 v) {
    unsigned int u; __builtin_memcpy(&u, &v, 4); return u;
}
__device__ __forceinline__ unsigned short f2h16(float f) {
    half_t h = (half_t)f;
    unsigned short u; __builtin_memcpy(&u, &h, 2); return u;
}
__device__ __forceinline__ float h16tof(unsigned short u) {
    half_t h; __builtin_memcpy(&h, &u, 2); return (float)h;
}

#if __has_builtin(__builtin_amdgcn_fdot2)
__device__ __forceinline__ float dot2(h2 a, h2 b, float c) {
    return __builtin_amdgcn_fdot2(a, b, c, false);
}
#else
__device__ __forceinline__ float dot2(h2 a, h2 b, float c) {
    return c + (float)a[0] * (float)b[0] + (float)a[1] * (float)b[1];
}
#endif

__device__ __forceinline__ float sigmoidf_(float x) {
    return 1.0f / (1.0f + __expf(-x));
}
__device__ __forceinline__ float tanhf_(float x) {
    return 1.0f - 2.0f / (__expf(2.0f * x) + 1.0f);
}

union W64 { unsigned long long u; h2 h[2]; };

// ---------------------------------------------------------------------------
// Kernel 1: xg packed f16: word (dir,t,col) = {gate row col, gate row col+512}
// ---------------------------------------------------------------------------
#define SBLK 16
__global__ __launch_bounds__(256) void xg_kernel(
    const int* __restrict__ sent, const float* __restrict__ emb,
    const float* __restrict__ w_ih_f, const float* __restrict__ b_f,
    const float* __restrict__ w_ih_b, const float* __restrict__ b_b,
    unsigned short* __restrict__ xg16s)   // viewed as ushort[2*S*512*2]
{
    const int dir = blockIdx.y;
    const int t0 = blockIdx.x * SBLK;
    const float* w_ih = dir ? w_ih_b : w_ih_f;
    const float* bias = dir ? b_b : b_f;

    __shared__ float embs[SBLK][E];   // 16 KB
    for (int p = threadIdx.x; p < SBLK * (E / 4); p += 256) {
        int r = p >> 6, kq = p & 63;
        int t = t0 + r;
        int tt = dir ? (S - 1 - t) : t;
        int tok = sent[tt];
        float4 v = *(const float4*)(emb + (size_t)tok * E + 4 * kq);
        *(float4*)&embs[r][4 * kq] = v;
    }
    __syncthreads();

    for (int jj = 0; jj < 4; ++jj) {
        int j = jj * 256 + threadIdx.x;
        const float* wrow = w_ih + (size_t)j * E;
        float bv = bias[j];
        float acc[SBLK];
        #pragma unroll
        for (int t = 0; t < SBLK; ++t) acc[t] = bv;

        for (int kc = 0; kc < E / 16; ++kc) {
            float w[16];
            float4 a0 = *(const float4*)(wrow + kc * 16);
            float4 a1 = *(const float4*)(wrow + kc * 16 + 4);
            float4 a2 = *(const float4*)(wrow + kc * 16 + 8);
            float4 a3 = *(const float4*)(wrow + kc * 16 + 12);
            w[0] = a0.x; w[1] = a0.y; w[2] = a0.z; w[3] = a0.w;
            w[4] = a1.x; w[5] = a1.y; w[6] = a1.z; w[7] = a1.w;
            w[8] = a2.x; w[9] = a2.y; w[10] = a2.z; w[11] = a2.w;
            w[12] = a3.x; w[13] = a3.y; w[14] = a3.z; w[15] = a3.w;
            #pragma unroll
            for (int t = 0; t < SBLK; ++t) {
                const float* er = &embs[t][kc * 16];
                float s = 0.f;
                #pragma unroll
                for (int q = 0; q < 16; ++q) s += w[q] * er[q];
                acc[t] += s;
            }
        }
        const int col = j & 511;
        const int hi = j >> 9;
        #pragma unroll
        for (int t = 0; t < SBLK; ++t) {
            size_t word = ((size_t)dir * S + (size_t)(t0 + t)) * 512 + col;
            xg16s[word * 2 + hi] = f2h16(acc[t]);
        }
    }
}

// ---------------------------------------------------------------------------
// Kernel 2: persistent per-direction LSTM. 2 blocks x 512 threads.
// ALL weights on-chip: pairs 0..99 in VGPRs (200 regs), 100..127 in LDS
// (114688 B). Dynamic LDS 117248 B -> 1 block/CU -> 256-reg budget.
// ---------------------------------------------------------------------------
#define RP 100                         // reg pairs per row
#define LSLOT 14                       // u64 slot-pairs per row-group (28 pairs)
#define WL_BYTES (2 * LSLOT * 512 * 8) // 114688
#define HB_OFF  WL_BYTES               // hbuf: 128 u32 = 512 B
#define FO_OFF  (WL_BYTES + 512)       // fo: 512 f32 = 2048 B
#define LSTM_LDS_BYTES (WL_BYTES + 512 + 2048)   // 117248

__global__ __launch_bounds__(512, 2) void lstm_kernel(
    const float* __restrict__ h0, const float* __restrict__ c0,
    const float* __restrict__ w_hh_f, const float* __restrict__ w_hh_b,
    const unsigned int* __restrict__ xg16, float* __restrict__ hs)
{
    extern __shared__ char smem[];
    unsigned long long* wl = (unsigned long long*)smem;       // [2][14][512]
    unsigned int* hbuf = (unsigned int*)(smem + HB_OFF);      // h as f16x2
    float* fo = (float*)(smem + FO_OFF);                      // f,o exchange

    const int dir = blockIdx.x;
    const int tid = threadIdx.x;
    const float* w_hh = dir ? w_hh_b : w_hh_f;
    const int r0 = tid, r1 = 512 + tid;

    // ---- load weights (f32 -> f16): 100 pairs -> regs, 28 pairs -> LDS ----
    h2 wr0[RP], wr1[RP];
    {
        const float* p0 = w_hh + (size_t)r0 * H;
        const float* p1 = w_hh + (size_t)r1 * H;
        #pragma unroll
        for (int p = 0; p < RP; ++p) {
            float2 a = *(const float2*)(p0 + 2 * p);
            float2 b = *(const float2*)(p1 + 2 * p);
            wr0[p] = f2h2(a.x, a.y);
            wr1[p] = f2h2(b.x, b.y);
        }
        #pragma unroll
        for (int d = 0; d < LSLOT; ++d) {
            float4 a = *(const float4*)(p0 + 2 * RP + 4 * d);
            W64 wa; wa.h[0] = f2h2(a.x, a.y); wa.h[1] = f2h2(a.z, a.w);
            wl[(0 * LSLOT + d) * 512 + tid] = wa.u;
            float4 b = *(const float4*)(p1 + 2 * RP + 4 * d);
            W64 wb; wb.h[0] = f2h2(b.x, b.y); wb.h[1] = f2h2(b.z, b.w);
            wl[(1 * LSLOT + d) * 512 + tid] = wb.u;
        }
    }

    float c = 0.f;
    if (tid < 256) c = c0[dir * H + tid];
    if (tid < 128) {
        float2 u = *(const float2*)(h0 + dir * H + 2 * tid);
        hbuf[tid] = h22u(f2h2(u.x, u.y));
    }
    __syncthreads();

    const unsigned int* xgp = xg16 + (size_t)dir * S * 512 + tid;
    const uint4* hb4 = (const uint4*)hbuf;
    half_t* hhalf = (half_t*)hbuf;

    unsigned int xgw = xgp[0];

    for (int t = 0; t < S; ++t) {
        int tn = (t + 1 < S) ? (t + 1) : t;
        unsigned int xgn = xgp[(size_t)tn * 512];

        float acc0 = 0.f, acc1 = 0.f;

        // pairs 0..99 from registers (25 chunks of 8 h-values)
        #pragma unroll
        for (int cc = 0; cc < 25; ++cc) {
            uint4 hv = hb4[cc];
            h2 hh0 = u2h2(hv.x), hh1 = u2h2(hv.y), hh2 = u2h2(hv.z), hh3 = u2h2(hv.w);
            acc0 = dot2(wr0[cc * 4 + 0], hh0, acc0);
            acc0 = dot2(wr0[cc * 4 + 1], hh1, acc0);
            acc0 = dot2(wr0[cc * 4 + 2], hh2, acc0);
            acc0 = dot2(wr0[cc * 4 + 3], hh3, acc0);
            acc1 = dot2(wr1[cc * 4 + 0], hh0, acc1);
            acc1 = dot2(wr1[cc * 4 + 1], hh1, acc1);
            acc1 = dot2(wr1[cc * 4 + 2], hh2, acc1);
            acc1 = dot2(wr1[cc * 4 + 3], hh3, acc1);
        }

        // pairs 100..127 from LDS (7 chunks)
        #pragma unroll
        for (int cc = 25; cc < 32; ++cc) {
            uint4 hv = hb4[cc];
            h2 hh0 = u2h2(hv.x), hh1 = u2h2(hv.y), hh2 = u2h2(hv.z), hh3 = u2h2(hv.w);
            const int d = (cc - 25) * 2;
            W64 a01, a23, b01, b23;
            a01.u = wl[(0 * LSLOT + d) * 512 + tid];
            a23.u = wl[(0 * LSLOT + d + 1) * 512 + tid];
            b01.u = wl[(1 * LSLOT + d) * 512 + tid];
            b23.u = wl[(1 * LSLOT + d + 1) * 512 + tid];
            acc0 = dot2(a01.h[0], hh0, acc0);
            acc0 = dot2(a01.h[1], hh1, acc0);
            acc0 = dot2(a23.h[0], hh2, acc0);
            acc0 = dot2(a23.h[1], hh3, acc0);
            acc1 = dot2(b01.h[0], hh0, acc1);
            acc1 = dot2(b01.h[1], hh1, acc1);
            acc1 = dot2(b23.h[0], hh2, acc1);
            acc1 = dot2(b23.h[1], hh3, acc1);
        }

        float g0 = h16tof((unsigned short)(xgw & 0xffffu)) + acc0;
        float g1 = h16tof((unsigned short)(xgw >> 16)) + acc1;
        float ig = 0.f, gg = 0.f;
        if (tid < 256) {
            ig = sigmoidf_(g0);     // input gate
            gg = tanhf_(g1);        // candidate
        } else {
            fo[tid - 256] = sigmoidf_(g0);          // forget gate
            fo[256 + (tid - 256)] = sigmoidf_(g1);  // output gate
        }
        __syncthreads();
        if (tid < 256) {
            float f = fo[tid], o = fo[256 + tid];
            c = f * c + ig * gg;
            float hv2 = o * tanhf_(c);
            int row = dir ? (S - 1 - t) : t;
            hs[(size_t)row * 512 + dir * 256 + tid] = hv2;
            hhalf[tid] = (half_t)hv2;
        }
        xgw = xgn;
        __syncthreads();
    }
}

// ---------------------------------------------------------------------------
// Kernel 3: feats[t][tag] = lin_b[tag] + sum_k hs[t][k] * lin_w[tag][k]
// ---------------------------------------------------------------------------
__global__ __launch_bounds__(256) void feats_kernel(
    const float* __restrict__ hs, const float* __restrict__ lin_w,
    const float* __restrict__ lin_b, float* __restrict__ feats)
{
    const int t0 = blockIdx.x * 8;
    __shared__ float rows[8][512];   // 16 KB
    for (int p = threadIdx.x; p < 8 * 128; p += 256) {
        int r = p >> 7, sg = p & 127;
        float4 v = *(const float4*)(hs + (size_t)(t0 + r) * 512 + sg * 4);
        *(float4*)&rows[r][sg * 4] = v;
    }
    __syncthreads();

    const int tl = threadIdx.x >> 5, tag = threadIdx.x & 31;
    const float* lw = lin_w + (size_t)tag * 512;
    float acc = lin_b[tag];
    for (int kc = 0; kc < 32; ++kc) {
        float4 a0 = *(const float4*)(lw + kc * 16);
        float4 a1 = *(const float4*)(lw + kc * 16 + 4);
        float4 a2 = *(const float4*)(lw + kc * 16 + 8);
        float4 a3 = *(const float4*)(lw + kc * 16 + 12);
        const float* er = &rows[tl][kc * 16];
        acc += a0.x * er[0] + a0.y * er[1] + a0.z * er[2] + a0.w * er[3];
        acc += a1.x * er[4] + a1.y * er[5] + a1.z * er[6] + a1.w * er[7];
        acc += a2.x * er[8] + a2.y * er[9] + a2.z * er[10] + a2.w * er[11];
        acc += a3.x * er[12] + a3.y * er[13] + a3.z * er[14] + a3.w * er[15];
    }
    feats[(size_t)(t0 + tl) * T + tag] = acc;
}

// ---------------------------------------------------------------------------
// Kernel 4: Viterbi scan (wave 0, register tournament tree, no volatile)
// + chunked-parallel backtrack. OUTPUT FLOAT32.
// ---------------------------------------------------------------------------
#define NC 64
#define CS 64
__global__ __launch_bounds__(256) void viterbi_kernel(
    const float* __restrict__ feats, const float* __restrict__ trans,
    unsigned char* __restrict__ gbp, float* __restrict__ out)
{
    __shared__ __align__(16) float fvs[32];
    __shared__ float fin[32];
    __shared__ unsigned char Mmap[NC][32];
    __shared__ int ent[NC];
    __shared__ int lastsh;

    const int tid = threadIdx.x;

    if (tid < 64) {
        const int nt = tid & 31, hf = tid >> 5;
        float tr[16];
        #pragma unroll
        for (int q = 0; q < 16; ++q) tr[q] = trans[nt * T + hf * 16 + q];

        if (hf == 0) fvs[nt] = (nt == START_TAG) ? 0.f : NEGV;
        asm volatile("" ::: "memory");   // order init write before loop reads

        float featv = feats[nt];   // t = 0
        for (int t = 0; t < S; ++t) {
            float featn = feats[(size_t)((t + 1 < S) ? (t + 1) : t) * T + nt];

            // read this half's 16 fv values (same wave wrote them; DS in-order)
            float4 v0 = *(const float4*)&fvs[hf * 16];
            float4 v1 = *(const float4*)&fvs[hf * 16 + 4];
            float4 v2 = *(const float4*)&fvs[hf * 16 + 8];
            float4 v3 = *(const float4*)&fvs[hf * 16 + 12];

            float s[16]; int id[16];
            s[0] = v0.x + tr[0];  s[1] = v0.y + tr[1];  s[2] = v0.z + tr[2];  s[3] = v0.w + tr[3];
            s[4] = v1.x + tr[4];  s[5] = v1.y + tr[5];  s[6] = v1.z + tr[6];  s[7] = v1.w + tr[7];
            s[8] = v2.x + tr[8];  s[9] = v2.y + tr[9];  s[10] = v2.z + tr[10]; s[11] = v2.w + tr[11];
            s[12] = v3.x + tr[12]; s[13] = v3.y + tr[13]; s[14] = v3.z + tr[14]; s[15] = v3.w + tr[15];
            #pragma unroll
            for (int q = 0; q < 16; ++q) id[q] = q;
            // tournament tree, ties -> lower index (first-max)
            #pragma unroll
            for (int w = 1; w < 16; w <<= 1) {
                #pragma unroll
                for (int q = 0; q < 16; q += 2 * w) {
                    if (s[q + w] > s[q]) { s[q] = s[q + w]; id[q] = id[q + w]; }
                }
            }
            float m = s[0];
            int bi = id[0] + hf * 16;

            float m2 = __shfl(m, tid ^ 32);
            int b2 = __shfl(bi, tid ^ 32);
            if (hf == 0) {
                if (m2 > m) { m = m2; bi = b2; }   // strict >: low half wins ties
                fvs[nt] = m + featv;
                gbp[t * T + nt] = (unsigned char)bi;
            }
            asm volatile("" ::: "memory");   // order write before next-iter reads
            featv = featn;
        }

        if (hf == 0) fin[nt] = fvs[nt] + trans[STOP_TAG * T + nt];
        asm volatile("" ::: "memory");
        if (tid == 0) {
            float bm = -3.0e38f; int bl = 0;
            for (int j = 0; j < T; ++j) {
                if (fin[j] > bm) { bm = fin[j]; bl = j; }
            }
            out[0] = bm;               // score as float32
            lastsh = bl;
        }
    }
    __syncthreads();

    // Phase A: per-chunk tag maps (walk each 64-step chunk from every end tag)
    {
        int st[8], cc[8];
        #pragma unroll
        for (int k = 0; k < 8; ++k) {
            int it = tid + k * 256;
            cc[k] = it >> 5; st[k] = it & 31;
        }
        for (int s = 0; s < CS; ++s) {
            #pragma unroll
            for (int k = 0; k < 8; ++k) {
                st[k] = gbp[(cc[k] * CS + CS - 1 - s) * T + st[k]];
            }
        }
        #pragma unroll
        for (int k = 0; k < 8; ++k) {
            Mmap[cc[k]][(tid + k * 256) & 31] = (unsigned char)st[k];
        }
    }
    __syncthreads();

    // Phase B: sequential composition of 64 chunk maps (1 thread)
    if (tid == 0) {
        int cur = lastsh;
        ent[NC - 1] = cur;
        for (int cchunk = NC - 1; cchunk > 0; --cchunk) {
            cur = Mmap[cchunk][cur];
            ent[cchunk - 1] = cur;
        }
    }
    __syncthreads();

    // Phase C: each chunk writes its path segment (float32 tags)
    if (tid < NC) {
        int cchunk = tid;
        int cur = ent[cchunk];
        for (int i = CS - 1; i >= 0; --i) {
            int t = cchunk * CS + i;
            out[1 + t] = (float)cur;
            cur = gbp[t * T + cur];
        }
    }
}

// ---------------------------------------------------------------------------
extern "C" void kernel_launch(void* const* d_in, const int* in_sizes, int n_in,
                              void* d_out, int out_size, void* d_ws, size_t ws_size,
                              hipStream_t stream)
{
    const int* sent      = (const int*)d_in[0];
    const float* h0      = (const float*)d_in[1];
    const float* c0      = (const float*)d_in[2];
    const float* emb     = (const float*)d_in[3];
    const float* w_ih_f  = (const float*)d_in[4];
    const float* w_hh_f  = (const float*)d_in[5];
    const float* b_f     = (const float*)d_in[6];
    const float* w_ih_b  = (const float*)d_in[7];
    const float* w_hh_b  = (const float*)d_in[8];
    const float* b_b     = (const float*)d_in[9];
    const float* lin_w   = (const float*)d_in[10];
    const float* lin_b   = (const float*)d_in[11];
    const float* trans   = (const float*)d_in[12];
    float* out = (float*)d_out;

    // workspace layout (~25 MB)
    unsigned int* xg16   = (unsigned int*)d_ws;                          // [2][S][512] u32 = 16 MB
    float* hs            = (float*)(xg16 + (size_t)2 * S * 512);         // [S][512] f32 = 8 MB
    float* feats         = hs + (size_t)S * 512;                         // [S][32] f32 = 0.5 MB
    unsigned char* gbp   = (unsigned char*)(feats + (size_t)S * T);      // [S][32] = 128 KB

    static int lds_set = 0;
    hipFuncSetAttribute((const void*)lstm_kernel,
                        hipFuncAttributeMaxDynamicSharedMemorySize, LSTM_LDS_BYTES);
    (void)lds_set;

    xg_kernel<<<dim3(S / SBLK, 2), 256, 0, stream>>>(sent, emb, w_ih_f, b_f, w_ih_b, b_b,
                                                     (unsigned short*)xg16);
    lstm_kernel<<<2, 512, LSTM_LDS_BYTES, stream>>>(h0, c0, w_hh_f, w_hh_b, xg16, hs);
    feats_kernel<<<S / 8, 256, 0, stream>>>(hs, lin_w, lin_b, feats);
    viterbi_kernel<<<1, 256, 0, stream>>>(feats, trans, gbp, out);
}

// Round 6
// 7187.214 us; speedup vs baseline: 1.3974x; 1.2156x over previous
//
#include <hip/hip_runtime.h>
#include <cstdint>
#include <cstddef>

#define S 4096
#define E 256
#define H 256
#define T 32
#define START_TAG 30
#define STOP_TAG 31
#define NEGV (-10000.0f)

typedef _Float16 half_t;
typedef _Float16 h2 __attribute__((ext_vector_type(2)));

__device__ __forceinline__ h2 f2h2(float a, float b) {
    h2 r; r[0] = (half_t)a; r[1] = (half_t)b; return r;
}
__device__ __forceinline__ h2 u2h2(unsigned int u) {
    h2 r; __builtin_memcpy(&r, &u, 4); return r;
}
__device__ __forceinline__ unsigned int h22u(h2 v) {
    unsigned int u; __builtin_memcpy(&u, &v, 4); return u;
}
__device__ __forceinline__ unsigned short f2h16(float f) {
    half_t h = (half_t)f;
    unsigned short u; __builtin_memcpy(&u, &h, 2); return u;
}
__device__ __forceinline__ float h16tof(unsigned short u) {
    half_t h; __builtin_memcpy(&h, &u, 2); return (float)h;
}

#if __has_builtin(__builtin_amdgcn_fdot2)
__device__ __forceinline__ float dot2(h2 a, h2 b, float c) {
    return __builtin_amdgcn_fdot2(a, b, c, false);
}
#else
__device__ __forceinline__ float dot2(h2 a, h2 b, float c) {
    return c + (float)a[0] * (float)b[0] + (float)a[1] * (float)b[1];
}
#endif

__device__ __forceinline__ float sigmoidf_(float x) {
    return 1.0f / (1.0f + __expf(-x));
}
__device__ __forceinline__ float tanhf_(float x) {
    return 1.0f - 2.0f / (__expf(2.0f * x) + 1.0f);
}

// pairwise lane exchange (lanes 2k <-> 2k+1) via DPP quad_perm [1,0,3,2]; pure VALU
__device__ __forceinline__ float dpp_xor1_add(float x) {
    int yi = __builtin_amdgcn_update_dpp(0, __float_as_int(x), 0xB1, 0xF, 0xF, true);
    return x + __int_as_float(yi);
}

// ---------------------------------------------------------------------------
// Kernel 1: xg packed f16 per (dir, t, unit): u64 = {i, f, g, o} pre-activations
// ---------------------------------------------------------------------------
#define SBLK 16
__global__ __launch_bounds__(256) void xg_kernel(
    const int* __restrict__ sent, const float* __restrict__ emb,
    const float* __restrict__ w_ih_f, const float* __restrict__ b_f,
    const float* __restrict__ w_ih_b, const float* __restrict__ b_b,
    unsigned short* __restrict__ xg16s)   // [2][S][256][4] ushort
{
    const int dir = blockIdx.y;
    const int t0 = blockIdx.x * SBLK;
    const float* w_ih = dir ? w_ih_b : w_ih_f;
    const float* bias = dir ? b_b : b_f;

    __shared__ float embs[SBLK][E];   // 16 KB
    for (int p = threadIdx.x; p < SBLK * (E / 4); p += 256) {
        int r = p >> 6, kq = p & 63;
        int t = t0 + r;
        int tt = dir ? (S - 1 - t) : t;
        int tok = sent[tt];
        float4 v = *(const float4*)(emb + (size_t)tok * E + 4 * kq);
        *(float4*)&embs[r][4 * kq] = v;
    }
    __syncthreads();

    for (int jj = 0; jj < 4; ++jj) {           // jj = gate index G
        int j = jj * 256 + threadIdx.x;        // gate row
        const float* wrow = w_ih + (size_t)j * E;
        float bv = bias[j];
        float acc[SBLK];
        #pragma unroll
        for (int t = 0; t < SBLK; ++t) acc[t] = bv;

        for (int kc = 0; kc < E / 16; ++kc) {
            float w[16];
            float4 a0 = *(const float4*)(wrow + kc * 16);
            float4 a1 = *(const float4*)(wrow + kc * 16 + 4);
            float4 a2 = *(const float4*)(wrow + kc * 16 + 8);
            float4 a3 = *(const float4*)(wrow + kc * 16 + 12);
            w[0] = a0.x; w[1] = a0.y; w[2] = a0.z; w[3] = a0.w;
            w[4] = a1.x; w[5] = a1.y; w[6] = a1.z; w[7] = a1.w;
            w[8] = a2.x; w[9] = a2.y; w[10] = a2.z; w[11] = a2.w;
            w[12] = a3.x; w[13] = a3.y; w[14] = a3.z; w[15] = a3.w;
            #pragma unroll
            for (int t = 0; t < SBLK; ++t) {
                const float* er = &embs[t][kc * 16];
                float s = 0.f;
                #pragma unroll
                for (int q = 0; q < 16; ++q) s += w[q] * er[q];
                acc[t] += s;
            }
        }
        const int u = threadIdx.x;   // unit
        #pragma unroll
        for (int t = 0; t < SBLK; ++t) {
            size_t base = (((size_t)dir * S + (size_t)(t0 + t)) * 256 + u) * 4 + jj;
            xg16s[base] = f2h16(acc[t]);
        }
    }
}

// ---------------------------------------------------------------------------
// Kernel 2: persistent per-direction LSTM. 2 blocks x 512 threads.
// Thread pair (2g,2g+1) owns unit g's rows {g, 256+g, 512+g, 768+g} (i,f,g~,o),
// K split by lane parity p (elements p*128..p*128+127).
// Weights: 52 pairs/row in regs, 12 pairs/row (3 uint4 chunks) in LDS.
// One barrier per step; h double-buffered in LDS; DPP pair-reduction.
// ---------------------------------------------------------------------------
#define WL4_ENT 12                               // per-thread uint4 LDS entries
#define WL4_BYTES (WL4_ENT * 512 * 16)           // 98304
#define LSTM_LDS_BYTES (WL4_BYTES + 2 * 128 * 4) // + double hbuf = 99328

__global__ __launch_bounds__(512, 2) void lstm_kernel(
    const float* __restrict__ h0, const float* __restrict__ c0,
    const float* __restrict__ w_hh_f, const float* __restrict__ w_hh_b,
    const unsigned long long* __restrict__ xgq, float* __restrict__ hs)
{
    extern __shared__ char smem[];
    uint4* wl4 = (uint4*)smem;                        // [12][512]
    unsigned int* hbuf = (unsigned int*)(smem + WL4_BYTES);  // [2][128] f16x2

    const int dir = blockIdx.x;
    const int tid = threadIdx.x;
    const int g = tid >> 1;          // unit 0..255
    const int p = tid & 1;           // K-half
    const float* w_hh = dir ? w_hh_b : w_hh_f;

    // rows for this unit: i, f, g~, o
    const int rows[4] = { g, 256 + g, 512 + g, 768 + g };

    // ---- load weights: 52 pairs/row -> regs, 12 pairs/row -> LDS ----
    h2 wrI[52], wrF[52], wrG[52], wrO[52];
    {
        #pragma unroll
        for (int r = 0; r < 4; ++r) {
            const float* pr = w_hh + (size_t)rows[r] * H + p * 128;
            h2* dst = (r == 0) ? wrI : (r == 1) ? wrF : (r == 2) ? wrG : wrO;
            #pragma unroll
            for (int q2 = 0; q2 < 26; ++q2) {       // pairs 2*q2, 2*q2+1
                float4 a = *(const float4*)(pr + 4 * q2);
                dst[2 * q2]     = f2h2(a.x, a.y);
                dst[2 * q2 + 1] = f2h2(a.z, a.w);
            }
            #pragma unroll
            for (int lc = 0; lc < 3; ++lc) {        // pairs 52+4lc .. 55+4lc
                float4 a = *(const float4*)(pr + 104 + 8 * lc);
                float4 b = *(const float4*)(pr + 108 + 8 * lc);
                uint4 w;
                w.x = h22u(f2h2(a.x, a.y));
                w.y = h22u(f2h2(a.z, a.w));
                w.z = h22u(f2h2(b.x, b.y));
                w.w = h22u(f2h2(b.z, b.w));
                wl4[(r * 3 + lc) * 512 + tid] = w;
            }
        }
    }

    float c = c0[dir * H + g];       // both lanes keep c redundantly
    if (tid < 128) {
        float2 u = *(const float2*)(h0 + dir * H + 2 * tid);
        hbuf[tid] = h22u(f2h2(u.x, u.y));      // buffer 0
    }
    __syncthreads();

    const unsigned long long* xgp = xgq + (size_t)dir * S * 256 + g;
    unsigned long long xgw = xgp[0];

    for (int t = 0; t < S; ++t) {
        int tn = (t + 1 < S) ? (t + 1) : t;
        unsigned long long xgn = xgp[(size_t)tn * 256];

        const int rbuf = t & 1;
        const uint4* hb4 = (const uint4*)(hbuf + rbuf * 128) + p * 16;

        float a0 = 0.f, a1 = 0.f, a2 = 0.f, a3 = 0.f;

        // chunks 0..12 from registers (pairs 0..51)
        #pragma unroll
        for (int cc = 0; cc < 13; ++cc) {
            uint4 hv = hb4[cc];
            h2 hh0 = u2h2(hv.x), hh1 = u2h2(hv.y), hh2 = u2h2(hv.z), hh3 = u2h2(hv.w);
            a0 = dot2(wrI[cc * 4 + 0], hh0, a0);
            a0 = dot2(wrI[cc * 4 + 1], hh1, a0);
            a0 = dot2(wrI[cc * 4 + 2], hh2, a0);
            a0 = dot2(wrI[cc * 4 + 3], hh3, a0);
            a1 = dot2(wrF[cc * 4 + 0], hh0, a1);
            a1 = dot2(wrF[cc * 4 + 1], hh1, a1);
            a1 = dot2(wrF[cc * 4 + 2], hh2, a1);
            a1 = dot2(wrF[cc * 4 + 3], hh3, a1);
            a2 = dot2(wrG[cc * 4 + 0], hh0, a2);
            a2 = dot2(wrG[cc * 4 + 1], hh1, a2);
            a2 = dot2(wrG[cc * 4 + 2], hh2, a2);
            a2 = dot2(wrG[cc * 4 + 3], hh3, a2);
            a3 = dot2(wrO[cc * 4 + 0], hh0, a3);
            a3 = dot2(wrO[cc * 4 + 1], hh1, a3);
            a3 = dot2(wrO[cc * 4 + 2], hh2, a3);
            a3 = dot2(wrO[cc * 4 + 3], hh3, a3);
        }
        // chunks 13..15 from LDS (pairs 52..63)
        #pragma unroll
        for (int lc = 0; lc < 3; ++lc) {
            uint4 hv = hb4[13 + lc];
            h2 hh0 = u2h2(hv.x), hh1 = u2h2(hv.y), hh2 = u2h2(hv.z), hh3 = u2h2(hv.w);
            uint4 wI = wl4[(0 * 3 + lc) * 512 + tid];
            uint4 wF = wl4[(1 * 3 + lc) * 512 + tid];
            uint4 wG = wl4[(2 * 3 + lc) * 512 + tid];
            uint4 wO = wl4[(3 * 3 + lc) * 512 + tid];
            a0 = dot2(u2h2(wI.x), hh0, a0);
            a0 = dot2(u2h2(wI.y), hh1, a0);
            a0 = dot2(u2h2(wI.z), hh2, a0);
            a0 = dot2(u2h2(wI.w), hh3, a0);
            a1 = dot2(u2h2(wF.x), hh0, a1);
            a1 = dot2(u2h2(wF.y), hh1, a1);
            a1 = dot2(u2h2(wF.z), hh2, a1);
            a1 = dot2(u2h2(wF.w), hh3, a1);
            a2 = dot2(u2h2(wG.x), hh0, a2);
            a2 = dot2(u2h2(wG.y), hh1, a2);
            a2 = dot2(u2h2(wG.z), hh2, a2);
            a2 = dot2(u2h2(wG.w), hh3, a2);
            a3 = dot2(u2h2(wO.x), hh0, a3);
            a3 = dot2(u2h2(wO.y), hh1, a3);
            a3 = dot2(u2h2(wO.z), hh2, a3);
            a3 = dot2(u2h2(wO.w), hh3, a3);
        }

        // pair reduction: both lanes get all 4 full gate sums
        float si = dpp_xor1_add(a0);
        float sf = dpp_xor1_add(a1);
        float sg = dpp_xor1_add(a2);
        float so = dpp_xor1_add(a3);

        unsigned int lo = (unsigned int)xgw;
        unsigned int hi = (unsigned int)(xgw >> 32);
        float gi = h16tof((unsigned short)(lo & 0xffffu)) + si;
        float gf = h16tof((unsigned short)(lo >> 16)) + sf;
        float gg = h16tof((unsigned short)(hi & 0xffffu)) + sg;
        float go = h16tof((unsigned short)(hi >> 16)) + so;

        float iv = sigmoidf_(gi);
        float fv = sigmoidf_(gf);
        float gv = tanhf_(gg);
        float ov = sigmoidf_(go);
        c = fv * c + iv * gv;
        float hv = ov * tanhf_(c);

        if (p == 0) {
            int row = dir ? (S - 1 - t) : t;
            hs[(size_t)row * 512 + dir * 256 + g] = hv;
            ((unsigned short*)(hbuf + ((t + 1) & 1) * 128))[g] = f2h16(hv);
        }
        xgw = xgn;
        __syncthreads();
    }
}

// ---------------------------------------------------------------------------
// Kernel 3: feats[t][tag] = lin_b[tag] + sum_k hs[t][k] * lin_w[tag][k]
// ---------------------------------------------------------------------------
__global__ __launch_bounds__(256) void feats_kernel(
    const float* __restrict__ hs, const float* __restrict__ lin_w,
    const float* __restrict__ lin_b, float* __restrict__ feats)
{
    const int t0 = blockIdx.x * 8;
    __shared__ float rows[8][512];   // 16 KB
    for (int p = threadIdx.x; p < 8 * 128; p += 256) {
        int r = p >> 7, sg = p & 127;
        float4 v = *(const float4*)(hs + (size_t)(t0 + r) * 512 + sg * 4);
        *(float4*)&rows[r][sg * 4] = v;
    }
    __syncthreads();

    const int tl = threadIdx.x >> 5, tag = threadIdx.x & 31;
    const float* lw = lin_w + (size_t)tag * 512;
    float acc = lin_b[tag];
    for (int kc = 0; kc < 32; ++kc) {
        float4 a0 = *(const float4*)(lw + kc * 16);
        float4 a1 = *(const float4*)(lw + kc * 16 + 4);
        float4 a2 = *(const float4*)(lw + kc * 16 + 8);
        float4 a3 = *(const float4*)(lw + kc * 16 + 12);
        const float* er = &rows[tl][kc * 16];
        acc += a0.x * er[0] + a0.y * er[1] + a0.z * er[2] + a0.w * er[3];
        acc += a1.x * er[4] + a1.y * er[5] + a1.z * er[6] + a1.w * er[7];
        acc += a2.x * er[8] + a2.y * er[9] + a2.z * er[10] + a2.w * er[11];
        acc += a3.x * er[12] + a3.y * er[13] + a3.z * er[14] + a3.w * er[15];
    }
    feats[(size_t)(t0 + tl) * T + tag] = acc;
}

// ---------------------------------------------------------------------------
// Kernel 4a: per-chunk (max,+) transfer matrices. Block c folds steps
// c*64..c*64+63 into M_c[32][32]; A_t[n][p] = trans[n][p] + feats[t][n].
// ---------------------------------------------------------------------------
#define VCS 64
#define VNC (S / VCS)    // 64
__global__ __launch_bounds__(256) void vit_chunk_kernel(
    const float* __restrict__ feats, const float* __restrict__ trans,
    float* __restrict__ gM)
{
    const int c = blockIdx.x;
    const int tid = threadIdx.x;
    const int n = tid >> 3, p0 = (tid & 7) * 4;
    __shared__ float Mb[2][32][36];   // padded rows (144 B, 16-aligned)

    float tr[32];
    #pragma unroll
    for (int k = 0; k < 32; ++k) tr[k] = trans[n * 32 + k];

    float f0 = feats[(size_t)(c * VCS) * 32 + n];
    float4 cur = { tr[p0] + f0, tr[p0 + 1] + f0, tr[p0 + 2] + f0, tr[p0 + 3] + f0 };
    *(float4*)&Mb[0][n][p0] = cur;
    __syncthreads();

    int rb = 0;
    for (int s = 1; s < VCS; ++s) {
        float fn = feats[(size_t)(c * VCS + s) * 32 + n];
        float4 acc = { -3.0e38f, -3.0e38f, -3.0e38f, -3.0e38f };
        #pragma unroll 8
        for (int k = 0; k < 32; ++k) {
            float4 mo = *(const float4*)&Mb[rb][k][p0];
            float tk = tr[k];
            acc.x = fmaxf(acc.x, tk + mo.x);
            acc.y = fmaxf(acc.y, tk + mo.y);
            acc.z = fmaxf(acc.z, tk + mo.z);
            acc.w = fmaxf(acc.w, tk + mo.w);
        }
        acc.x += fn; acc.y += fn; acc.z += fn; acc.w += fn;
        cur = acc;
        *(float4*)&Mb[rb ^ 1][n][p0] = acc;
        rb ^= 1;
        __syncthreads();
    }
    *(float4*)(gM + (size_t)c * 1024 + n * 32 + p0) = cur;
}

// ---------------------------------------------------------------------------
// Kernel 4b: prefix-apply chunk matrices -> boundary fvs; chunk-parallel
// rescan for backpointers; 3-phase backtrack. OUTPUT FLOAT32.
// ---------------------------------------------------------------------------
__global__ __launch_bounds__(1024) void vit_combine_kernel(
    const float* __restrict__ feats, const float* __restrict__ trans,
    const float* __restrict__ gM, unsigned char* __restrict__ gbp,
    float* __restrict__ out)
{
    __shared__ float MS[1024];
    __shared__ __align__(16) float bfv[VNC + 1][32];
    __shared__ __align__(16) float fvc[VNC][32];
    __shared__ unsigned char Mmap[VNC][32];
    __shared__ int ent[VNC];
    __shared__ int lastsh;

    const int tid = threadIdx.x;

    // P0: boundary fvs via sequential matrix application
    if (tid < 32) bfv[0][tid] = (tid == START_TAG) ? 0.f : NEGV;
    __syncthreads();
    for (int c = 0; c < VNC; ++c) {
        MS[tid] = gM[(size_t)c * 1024 + tid];
        __syncthreads();
        if (tid < 32) {
            float m = -3.0e38f;
            #pragma unroll 8
            for (int k = 0; k < 32; ++k)
                m = fmaxf(m, MS[tid * 32 + k] + bfv[c][k]);
            bfv[c + 1][tid] = m;
        }
        __syncthreads();
    }
    if (tid == 0) {
        float bm = -3.0e38f; int bl = 0;
        for (int j = 0; j < 32; ++j) {
            float s2 = bfv[VNC][j] + trans[STOP_TAG * 32 + j];
            if (s2 > bm) { bm = s2; bl = j; }
        }
        out[0] = bm;
        lastsh = bl;
    }
    __syncthreads();

    // P1: per-chunk rescan (exact scan from boundary fv) -> backpointers.
    // 32 threads per chunk (half-wave -> wave-lockstep LDS, no barriers).
    for (int pass = 0; pass < 2; ++pass) {
        const int c = (tid >> 5) + pass * 32;
        const int nt = tid & 31;
        float tr[32];
        #pragma unroll
        for (int k = 0; k < 32; ++k) tr[k] = trans[nt * 32 + k];

        fvc[c][nt] = bfv[c][nt];
        __builtin_amdgcn_wave_barrier();
        asm volatile("" ::: "memory");

        for (int s = 0; s < VCS; ++s) {
            const int t = c * VCS + s;
            float4 v0 = *(const float4*)&fvc[c][0];
            float4 v1 = *(const float4*)&fvc[c][4];
            float4 v2 = *(const float4*)&fvc[c][8];
            float4 v3 = *(const float4*)&fvc[c][12];
            float4 v4 = *(const float4*)&fvc[c][16];
            float4 v5 = *(const float4*)&fvc[c][20];
            float4 v6 = *(const float4*)&fvc[c][24];
            float4 v7 = *(const float4*)&fvc[c][28];
            float fvv[32] = { v0.x, v0.y, v0.z, v0.w, v1.x, v1.y, v1.z, v1.w,
                              v2.x, v2.y, v2.z, v2.w, v3.x, v3.y, v3.z, v3.w,
                              v4.x, v4.y, v4.z, v4.w, v5.x, v5.y, v5.z, v5.w,
                              v6.x, v6.y, v6.z, v6.w, v7.x, v7.y, v7.z, v7.w };
            float m = -3.0e38f; int bi = 0;
            #pragma unroll
            for (int k = 0; k < 32; ++k) {
                float s2 = fvv[k] + tr[k];
                if (s2 > m) { m = s2; bi = k; }     // first-max
            }
            m += feats[(size_t)t * 32 + nt];
            gbp[(size_t)t * 32 + nt] = (unsigned char)bi;
            __builtin_amdgcn_wave_barrier();
            asm volatile("" ::: "memory");
            fvc[c][nt] = m;
            __builtin_amdgcn_wave_barrier();
            asm volatile("" ::: "memory");
        }
        __syncthreads();
    }

    // Phase A: per-chunk entry->exit tag maps
    {
        #pragma unroll
        for (int kk = 0; kk < 2; ++kk) {
            int it = tid + kk * 1024;
            int cc = it >> 5, st = it & 31;
            int cur = st;
            for (int s = VCS - 1; s >= 0; --s)
                cur = gbp[(size_t)(cc * VCS + s) * 32 + cur];
            Mmap[cc][st] = (unsigned char)cur;
        }
    }
    __syncthreads();

    // Phase B: compose chunk maps
    if (tid == 0) {
        int cur = lastsh;
        ent[VNC - 1] = cur;
        for (int cchunk = VNC - 1; cchunk > 0; --cchunk) {
            cur = Mmap[cchunk][cur];
            ent[cchunk - 1] = cur;
        }
    }
    __syncthreads();

    // Phase C: write path
    if (tid < VNC) {
        int cur = ent[tid];
        for (int i = VCS - 1; i >= 0; --i) {
            int t = tid * VCS + i;
            out[1 + t] = (float)cur;
            cur = gbp[(size_t)t * 32 + cur];
        }
    }
}

// ---------------------------------------------------------------------------
extern "C" void kernel_launch(void* const* d_in, const int* in_sizes, int n_in,
                              void* d_out, int out_size, void* d_ws, size_t ws_size,
                              hipStream_t stream)
{
    const int* sent      = (const int*)d_in[0];
    const float* h0      = (const float*)d_in[1];
    const float* c0      = (const float*)d_in[2];
    const float* emb     = (const float*)d_in[3];
    const float* w_ih_f  = (const float*)d_in[4];
    const float* w_hh_f  = (const float*)d_in[5];
    const float* b_f     = (const float*)d_in[6];
    const float* w_ih_b  = (const float*)d_in[7];
    const float* w_hh_b  = (const float*)d_in[8];
    const float* b_b     = (const float*)d_in[9];
    const float* lin_w   = (const float*)d_in[10];
    const float* lin_b   = (const float*)d_in[11];
    const float* trans   = (const float*)d_in[12];
    float* out = (float*)d_out;

    // workspace layout (~25 MB)
    unsigned long long* xgq = (unsigned long long*)d_ws;              // [2][S][256] u64 = 16 MB
    float* hs    = (float*)(xgq + (size_t)2 * S * 256);               // [S][512] f32 = 8 MB
    float* feats = hs + (size_t)S * 512;                              // [S][32] f32 = 0.5 MB
    float* gM    = feats + (size_t)S * T;                             // [64][1024] f32 = 256 KB
    unsigned char* gbp = (unsigned char*)(gM + (size_t)VNC * 1024);   // [S][32] = 128 KB

    hipFuncSetAttribute((const void*)lstm_kernel,
                        hipFuncAttributeMaxDynamicSharedMemorySize, LSTM_LDS_BYTES);

    xg_kernel<<<dim3(S / SBLK, 2), 256, 0, stream>>>(sent, emb, w_ih_f, b_f, w_ih_b, b_b,
                                                     (unsigned short*)xgq);
    lstm_kernel<<<2, 512, LSTM_LDS_BYTES, stream>>>(h0, c0, w_hh_f, w_hh_b, xgq, hs);
    feats_kernel<<<S / 8, 256, 0, stream>>>(hs, lin_w, lin_b, feats);
    vit_chunk_kernel<<<VNC, 256, 0, stream>>>(feats, trans, gM);
    vit_combine_kernel<<<1, 1024, 0, stream>>>(feats, trans, gM, gbp, out);
}